// Round 2
// baseline (120.404 us; speedup 1.0000x reference)
//
#include <hip/hip_runtime.h>

typedef unsigned short u16;
typedef unsigned int   u32;

typedef short s8v  __attribute__((ext_vector_type(8)));   // 8 bf16 (4 VGPR)
typedef float f16v __attribute__((ext_vector_type(16)));  // 32x32 acc

#define ROWB 5280                 // staged row: 66 px * 80 B (pad 64->80 kills bank conflicts)
#define RING_BYTES (8 * ROWB)     // 42240 B ring of 8 input rows

__device__ inline u16 f2bf(float f) {
    u32 u = __builtin_bit_cast(u32, f);
    u += 0x7FFFu + ((u >> 16) & 1u);   // RNE; inputs finite
    return (u16)(u >> 16);
}

// Fused: NCHW f32 -> (LDS ring, NHWC bf16, zero-padded) -> implicit-GEMM MFMA conv.
// Block: 256 thr = 4 waves; owns 32o x 64w x 16h. Grid: 16n * 16hs * 4ws = 1024.
__global__ __launch_bounds__(256, 3) void k_fused(const float* __restrict__ x,
                                                  const float* __restrict__ wgt,
                                                  const float* __restrict__ bias,
                                                  const float* __restrict__ scale_p,
                                                  float* __restrict__ out) {
    __shared__ __align__(16) char lds[RING_BYTES];

    const int b    = blockIdx.x;
    const int wb   = b & 3;
    const int hs   = (b >> 2) & 15;
    const int n    = b >> 6;
    const int w0   = wb << 6;
    const int h0   = hs << 4;
    const int t    = threadIdx.x;
    const int l    = t & 63;
    const int wave = t >> 6;
    const int g    = l >> 5;
    const int ln   = l & 31;

    // ---- weight repack (LDS overlay, used once): [o][c][9] f32 -> [tap][o*32+c] bf16
    {
        u16* wl = (u16*)lds;
        #pragma unroll
        for (int k = 0; k < 36; ++k) {                 // 9216 = 36*256, coalesced src
            const int idx = t + (k << 8);
            const int tap = idx % 9;
            const int oc  = idx / 9;
            wl[tap * 1024 + oc] = f2bf(wgt[idx]);
        }
    }
    __syncthreads();

    // A fragments: wt[tap][o=ln][c = q*16 + g*8 + e]
    s8v A[9][2];
    {
        const u16* wl = (const u16*)lds;
        #pragma unroll
        for (int tap = 0; tap < 9; ++tap)
            #pragma unroll
            for (int q = 0; q < 2; ++q)
                A[tap][q] = *(const s8v*)(wl + tap * 1024 + ln * 32 + q * 16 + g * 8);
    }
    const float scale = scale_p[0];
    float bias_r[16];
    #pragma unroll
    for (int r = 0; r < 16; ++r) bias_r[r] = bias[(r & 3) + 8 * (r >> 2) + 4 * g];
    __syncthreads();   // overlay free; ring staging may begin

    // ---- stage nrows input rows (base..base+nrows-1) into ring; zeros for OOB
    auto stage = [&](int base, int nrows) {
        const int tot = nrows * 1056;                  // 66 px * 16 u32 per row
        for (int idx = t; idx < tot; idx += 256) {
            const int rr  = idx / 1056;
            const int rem = idx - rr * 1056;
            const int cp  = rem / 66;                  // channel pair 0..15
            const int ws  = rem - cp * 66;             // staged px 0..65
            const int hin = base + rr;
            const int wg  = w0 - 1 + ws;
            u32 val = 0;
            if (hin >= 0 && hin < 256 && wg >= 0 && wg < 256) {
                const float* p = x + (((n * 32 + (cp << 1)) * 256 + hin) * 256 + wg);
                const float f0 = p[0];
                const float f1 = p[65536];             // c+1
                val = (u32)f2bf(f0) | ((u32)f2bf(f1) << 16);
            }
            *(u32*)(lds + ((hin + 8) & 7) * ROWB + ws * 80 + cp * 4) = val;
        }
    };

    stage(h0 - 1, 6);                                  // rows h0-1 .. h0+4
    __syncthreads();

    #pragma unroll
    for (int i = 0; i < 4; ++i) {
        const int h = h0 + (i << 2) + wave;            // this wave's output row

        f16v acc0, acc1;
        #pragma unroll
        for (int r = 0; r < 16; ++r) { acc0[r] = 0.f; acc1[r] = 0.f; }

        #pragma unroll
        for (int kh = 0; kh < 3; ++kh) {
            const int hin = h + kh - 1;
            const char* rowp = lds + ((hin + 8) & 7) * ROWB;
            #pragma unroll
            for (int kw = 0; kw < 3; ++kw) {
                const char* colp = rowp + (ln + kw) * 80 + g * 16;
                const int tap = kh * 3 + kw;
                #pragma unroll
                for (int q = 0; q < 2; ++q) {
                    const s8v b0 = *(const s8v*)(colp + q * 32);
                    const s8v b1 = *(const s8v*)(colp + 32 * 80 + q * 32);
                    acc0 = __builtin_amdgcn_mfma_f32_32x32x16_bf16(A[tap][q], b0, acc0, 0, 0, 0);
                    acc1 = __builtin_amdgcn_mfma_f32_32x32x16_bf16(A[tap][q], b1, acc1, 0, 0, 0);
                }
            }
        }

        // epilogue: D col(px)=ln, row(o)=(r&3)+8*(r>>2)+4*g
        float* op = out + ((size_t)(n * 32) * 65536) + h * 256 + w0 + ln;
        #pragma unroll
        for (int r = 0; r < 16; ++r) {
            const int o = (r & 3) + 8 * (r >> 2) + 4 * g;
            op[o * 65536]      = scale * acc0[r] + bias_r[r];
            op[o * 65536 + 32] = scale * acc1[r] + bias_r[r];
        }

        if (i < 3) {
            __syncthreads();                           // all waves done reading old rows
            stage(h0 + (i << 2) + 5, 4);               // next 4 rows into freed slots
            __syncthreads();                           // writes visible
        }
    }
}

extern "C" void kernel_launch(void* const* d_in, const int* in_sizes, int n_in,
                              void* d_out, int out_size, void* d_ws, size_t ws_size,
                              hipStream_t stream) {
    const float* x     = (const float*)d_in[0];
    const float* wgt   = (const float*)d_in[1];
    const float* bias  = (const float*)d_in[2];
    const float* scale = (const float*)d_in[3];
    float* out = (float*)d_out;
    k_fused<<<dim3(1024), dim3(256), 0, stream>>>(x, wgt, bias, scale, out);
}

// Round 4
// 67.630 us; speedup vs baseline: 1.7803x; 1.7803x over previous
//
#include <hip/hip_runtime.h>

typedef unsigned short u16;
typedef unsigned int   u32;
typedef short s8v  __attribute__((ext_vector_type(8)));   // 8 bf16 (4 VGPR)
typedef float f16v __attribute__((ext_vector_type(16)));  // 32x32 acc

#define ROWBYTES 4224                 // 4 c-chunks * (66 px * 16 B)
#define NROWS    18
#define LDS_BYTES (NROWS * ROWBYTES)  // 76032 -> 2 blocks/CU

__device__ inline u16 f2bf(float f) {
    u32 u = __builtin_bit_cast(u32, f);
    u += 0x7FFFu + ((u >> 16) & 1u);   // RNE; inputs finite
    return (u16)(u >> 16);
}
__device__ inline u32 pk2(float lo, float hi) {           // 2xf32 -> packed bf16x2 (RNE)
    return (u32)f2bf(lo) | ((u32)f2bf(hi) << 16);
}

// Fused conv: stage full 18-row NHWC-bf16 tile to LDS (chunked layout,
// conflict-free b128 reads), ONE barrier, then 16 output rows of MFMA.
// Block: 256 thr = 4 waves; owns 32o x 64w x 16h. Grid: 16n*16hs*4wb = 1024.
__global__ __launch_bounds__(256, 2) void k_fused(const float* __restrict__ x,
                                                  const float* __restrict__ wgt,
                                                  const float* __restrict__ bias,
                                                  const float* __restrict__ scale_p,
                                                  float* __restrict__ out) {
    __shared__ __align__(16) char lds[LDS_BYTES];

    const int b    = blockIdx.x;
    const int wb   = b & 3;
    const int hs   = (b >> 2) & 15;
    const int n    = b >> 6;
    const int w0   = wb << 6;
    const int h0   = hs << 4;
    const int t    = threadIdx.x;
    const int l    = t & 63;
    const int wave = t >> 6;
    const int g    = l >> 5;
    const int ln   = l & 31;

    // ---- weight repack into LDS overlay: [o][c][9] f32 -> [tap][o*32+c] bf16
    {
        u16* wl = (u16*)lds;
        #pragma unroll
        for (int k = 0; k < 36; ++k) {
            const int idx = t + (k << 8);
            const int tap = idx % 9;
            const int oc  = idx / 9;
            wl[tap * 1024 + oc] = f2bf(wgt[idx]);
        }
    }
    __syncthreads();

    // A frags: wt[tap][o=ln][c = q*16 + g*8 + e]
    s8v A[9][2];
    {
        const u16* wl = (const u16*)lds;
        #pragma unroll
        for (int tap = 0; tap < 9; ++tap)
            #pragma unroll
            for (int q = 0; q < 2; ++q)
                A[tap][q] = *(const s8v*)(wl + tap * 1024 + ln * 32 + q * 16 + g * 8);
    }
    const float scale = scale_p[0];
    float bias_r[16];
    #pragma unroll
    for (int rg = 0; rg < 16; ++rg) bias_r[rg] = bias[(rg & 3) + 8 * (rg >> 2) + 4 * g];
    __syncthreads();   // weight overlay free

    // ---- stage 18 input rows (h0-1 .. h0+16), zero-filled OOB; shift-only addressing.
    // LDS layout per row: chunk(c>>3)*1056 + ps*16 + (c&7)*2, ps = staged px (wg = w0-1+ps)
    const float* xbase = x + ((size_t)n << 21);           // n*32*65536
    for (int r = 0; r < NROWS; ++r) {
        const int hin = h0 - 1 + r;
        const bool hv = (hin >= 0) && (hin < 256);
        const float* xrow = xbase + (size_t)hin * 256;
        char* lrow = lds + r * ROWBYTES;
        #pragma unroll
        for (int k = 0; k < 2; ++k) {
            const int idx = t + (k << 8);                 // 0..511
            const int cp  = idx >> 5;                     // channel pair 0..15
            const int ph  = idx & 31;                     // px-pair 0..31
            float2 va{0.f, 0.f}, vb{0.f, 0.f};
            if (hv) {
                const float* p = xrow + cp * 131072 + w0 + (ph << 1);
                va = *(const float2*)p;                   // c = 2cp
                vb = *(const float2*)(p + 65536);         // c = 2cp+1
            }
            char* dst = lrow + (cp >> 2) * 1056 + ((1 + (ph << 1)) << 4) + ((cp & 3) << 2);
            *(u32*)dst        = pk2(va.x, vb.x);          // ps = 1+2ph
            *(u32*)(dst + 16) = pk2(va.y, vb.y);          // ps = 2+2ph
        }
    }
    // halo columns ps=0 (wg=w0-1) and ps=65 (wg=w0+64): 18*2*16 = 576 u32
    for (int idx = t; idx < 576; idx += 256) {
        const int r    = idx >> 5;
        const int side = (idx >> 4) & 1;
        const int cp   = idx & 15;
        const int hin  = h0 - 1 + r;
        const int wg   = w0 - 1 + side * 65;
        float a = 0.f, c2 = 0.f;
        if (hin >= 0 && hin < 256 && wg >= 0 && wg < 256) {
            const float* p = xbase + (size_t)hin * 256 + cp * 131072 + wg;
            a  = p[0];
            c2 = p[65536];
        }
        *(u32*)(lds + r * ROWBYTES + (cp >> 2) * 1056 + side * 1040 + ((cp & 3) << 2)) = pk2(a, c2);
    }
    __syncthreads();   // the only full barrier before compute

    // ---- compute: each wave does 4 consecutive output rows, barrier-free
    #pragma unroll
    for (int i = 0; i < 4; ++i) {
        const int hr = (wave << 2) + i;

        f16v acc0, acc1;
        #pragma unroll
        for (int rg = 0; rg < 16; ++rg) { acc0[rg] = 0.f; acc1[rg] = 0.f; }

        #pragma unroll
        for (int kh = 0; kh < 3; ++kh) {
            const char* rowp = lds + (hr + kh) * ROWBYTES + g * 1056 + (ln << 4);
            #pragma unroll
            for (int kw = 0; kw < 3; ++kw) {
                const int tap = kh * 3 + kw;
                #pragma unroll
                for (int q = 0; q < 2; ++q) {
                    const char* pB = rowp + q * 2112 + (kw << 4);
                    const s8v b0 = *(const s8v*)pB;           // px = ln+kw
                    const s8v b1 = *(const s8v*)(pB + 512);   // px = ln+32+kw
                    acc0 = __builtin_amdgcn_mfma_f32_32x32x16_bf16(A[tap][q], b0, acc0, 0, 0, 0);
                    acc1 = __builtin_amdgcn_mfma_f32_32x32x16_bf16(A[tap][q], b1, acc1, 0, 0, 0);
                }
            }
        }

        // epilogue: D col(px)=ln, row(o)=(rg&3)+8*(rg>>2)+4*g
        const int h = h0 + hr;
        float* op = out + ((size_t)n << 21) + (size_t)h * 256 + w0 + ln;
        #pragma unroll
        for (int rg = 0; rg < 16; ++rg) {
            const int o = (rg & 3) + 8 * (rg >> 2) + 4 * g;
            op[(size_t)o * 65536]      = scale * acc0[rg] + bias_r[rg];
            op[(size_t)o * 65536 + 32] = scale * acc1[rg] + bias_r[rg];
        }
    }
}

extern "C" void kernel_launch(void* const* d_in, const int* in_sizes, int n_in,
                              void* d_out, int out_size, void* d_ws, size_t ws_size,
                              hipStream_t stream) {
    const float* x     = (const float*)d_in[0];
    const float* wgt   = (const float*)d_in[1];
    const float* bias  = (const float*)d_in[2];
    const float* scale = (const float*)d_in[3];
    float* out = (float*)d_out;
    k_fused<<<dim3(1024), dim3(256), 0, stream>>>(x, wgt, bias, scale, out);
}